// Round 1
// baseline (452.212 us; speedup 1.0000x reference)
//
#include <hip/hip_runtime.h>
#include <math.h>

#define Bsz 8
#define Nn  2048
#define Ff  256

// ---------------- k_pre: mask = sigmoid(10*(A-thr)); g = mask / (D+1e-5), diag(D)=1 ----------
__global__ __launch_bounds__(256) void k_pre(const float* __restrict__ Ageo,
                                             const float* __restrict__ Dm,
                                             const float* __restrict__ thr_p,
                                             float* __restrict__ mask,
                                             float* __restrict__ g) {
    int idx4 = blockIdx.x * 256 + threadIdx.x;          // float4 index, 0..N*N/4-1
    float thr = thr_p[0];
    float4 a = ((const float4*)Ageo)[idx4];
    float4 d = ((const float4*)Dm)[idx4];
    int i  = idx4 >> 9;                                  // row (N/4 = 512 float4 per row)
    int j0 = (idx4 & 511) << 2;
    float av[4] = {a.x, a.y, a.z, a.w};
    float dv[4] = {d.x, d.y, d.z, d.w};
    float mo[4], go[4];
#pragma unroll
    for (int k = 0; k < 4; k++) {
        float dd  = (j0 + k == i) ? 1.0f : dv[k];
        float inv = 1.0f / (dd + 1e-5f);
        float mk  = 1.0f / (1.0f + __expf(-10.0f * (av[k] - thr)));
        mo[k] = mk;
        go[k] = mk * inv;
    }
    ((float4*)mask)[idx4] = make_float4(mo[0], mo[1], mo[2], mo[3]);
    ((float4*)g)[idx4]    = make_float4(go[0], go[1], go[2], go[3]);
}

// ---------------- k_wt: Wt[f][o] = W[o][f] ----------------
__global__ __launch_bounds__(256) void k_wt(const float* __restrict__ W,
                                            float* __restrict__ Wt) {
    int o = blockIdx.x;
    int f = threadIdx.x;
    Wt[f * Ff + o] = W[o * Ff + f];
}

// ---------------- k_h: h = X @ W^T + b ; s1 = h.a1 ; s2 = h.a2 --------------
// one wave computes 8 rows; lane owns 4 output cols (o0..o0+3)
__global__ __launch_bounds__(256) void k_h(const float* __restrict__ X,
                                           const float* __restrict__ Wt,
                                           const float* __restrict__ Wb,
                                           const float* __restrict__ a1,
                                           const float* __restrict__ a2,
                                           float* __restrict__ h,
                                           float* __restrict__ s1,
                                           float* __restrict__ s2) {
    int wid  = blockIdx.x * 4 + (threadIdx.x >> 6);
    int lane = threadIdx.x & 63;
    int r0   = wid * 8;                 // global row base, 0..16376
    int o0   = lane * 4;

    float4 acc[8];
#pragma unroll
    for (int r = 0; r < 8; r++) acc[r] = make_float4(0.f, 0.f, 0.f, 0.f);

    for (int f0 = 0; f0 < Ff; f0 += 4) {
        float4 wv0 = *(const float4*)&Wt[(f0 + 0) * Ff + o0];
        float4 wv1 = *(const float4*)&Wt[(f0 + 1) * Ff + o0];
        float4 wv2 = *(const float4*)&Wt[(f0 + 2) * Ff + o0];
        float4 wv3 = *(const float4*)&Wt[(f0 + 3) * Ff + o0];
#pragma unroll
        for (int r = 0; r < 8; r++) {
            float4 xv = *(const float4*)&X[(size_t)(r0 + r) * Ff + f0];
            acc[r].x += xv.x * wv0.x + xv.y * wv1.x + xv.z * wv2.x + xv.w * wv3.x;
            acc[r].y += xv.x * wv0.y + xv.y * wv1.y + xv.z * wv2.y + xv.w * wv3.y;
            acc[r].z += xv.x * wv0.z + xv.y * wv1.z + xv.z * wv2.z + xv.w * wv3.z;
            acc[r].w += xv.x * wv0.w + xv.y * wv1.w + xv.z * wv2.w + xv.w * wv3.w;
        }
    }

    float4 wb  = *(const float4*)&Wb[o0];
    float4 a1v = *(const float4*)&a1[o0];
    float4 a2v = *(const float4*)&a2[o0];

#pragma unroll
    for (int r = 0; r < 8; r++) {
        float4 hv = make_float4(acc[r].x + wb.x, acc[r].y + wb.y,
                                acc[r].z + wb.z, acc[r].w + wb.w);
        *(float4*)&h[(size_t)(r0 + r) * Ff + o0] = hv;
        float d1 = hv.x * a1v.x + hv.y * a1v.y + hv.z * a1v.z + hv.w * a1v.w;
        float d2 = hv.x * a2v.x + hv.y * a2v.y + hv.z * a2v.z + hv.w * a2v.w;
#pragma unroll
        for (int d = 32; d; d >>= 1) {
            d1 += __shfl_xor(d1, d);
            d2 += __shfl_xor(d2, d);
        }
        if (lane == 0) {
            s1[r0 + r] = d1;
            s2[r0 + r] = d2;
        }
    }
}

// ---------------- k_attn: fused scores + online softmax + PV -----------------
// block: 256 threads = 4 waves; 32 query rows per block (8 per wave)
// chunk: 64 keys; h-chunk staged in LDS (swizzled), PV acc in registers
__global__ __launch_bounds__(256) void k_attn(const float* __restrict__ h,
                                              const float* __restrict__ s1,
                                              const float* __restrict__ s2,
                                              const float* __restrict__ mask,
                                              const float* __restrict__ g,
                                              const float* __restrict__ ab_p,
                                              float* __restrict__ out) {
    __shared__ float4 hs4[64][64];      // 64 KB, [key][f-float4], swizzled within fg-group
    __shared__ float  ps[32][68];       // p values, padded: stride 68 -> 8 distinct banks
    __shared__ float  wsc[32];          // per-row rescale factor
    __shared__ float  winv[32];         // per-row 1/denominator

    const int b    = blockIdx.y;
    const int i0   = blockIdx.x * 32;
    const int tid  = threadIdx.x;
    const int lane = tid & 63;
    const int rg   = tid >> 6;          // wave id: rows rg*8 .. rg*8+7
    const int r_pv = tid >> 3;          // PV row 0..31 (same wave as e-phase rows)
    const int fg   = tid & 7;           // PV f-group: f = fg*32 .. fg*32+31
    const float ab = ab_p[0];

    float s1v[8];
#pragma unroll
    for (int r = 0; r < 8; r++) s1v[r] = s1[b * Nn + i0 + rg * 8 + r];

    float m[8], l[8];
#pragma unroll
    for (int r = 0; r < 8; r++) { m[r] = -INFINITY; l[r] = 0.f; }
    float4 acc[8];
#pragma unroll
    for (int q = 0; q < 8; q++) acc[q] = make_float4(0.f, 0.f, 0.f, 0.f);

    for (int j0 = 0; j0 < Nn; j0 += 64) {
        __syncthreads();                       // protect hs4 from previous PV readers
        // ---- stage h[b, j0..j0+63, :] into LDS (swizzled) ----
#pragma unroll
        for (int k = 0; k < 16; k++) {
            int idx = tid + k * 256;
            int row = idx >> 6;
            int c   = idx & 63;                // float4 col 0..63
            int fgs = c >> 3, qs = c & 7;
            float4 v = *(const float4*)&h[((size_t)(b * Nn + j0 + row)) * Ff + c * 4];
            hs4[row][fgs * 8 + ((qs + fgs) & 7)] = v;
        }
        __syncthreads();

        // ---- scores for 8 rows of this wave; lane handles key j0+lane ----
        float p8[8];
        float s2j = s2[b * Nn + j0 + lane];
#pragma unroll
        for (int r = 0; r < 8; r++) {
            int gi   = i0 + rg * 8 + r;
            float mk = mask[(size_t)gi * Nn + j0 + lane];
            float gg = g[(size_t)gi * Nn + j0 + lane];
            float s  = s1v[r] + s2j + ab;
            s = (s > 0.f) ? s : 0.1f * s;
            p8[r] = s * mk + gg;
        }
        // ---- online softmax per row (wave-local) ----
#pragma unroll
        for (int r = 0; r < 8; r++) {
            float cm = p8[r];
#pragma unroll
            for (int d = 32; d; d >>= 1) cm = fmaxf(cm, __shfl_xor(cm, d));
            float nm = fmaxf(m[r], cm);
            float sc = __expf(m[r] - nm);
            m[r] = nm;
            float p = __expf(p8[r] - nm);
            l[r] = l[r] * sc + p;
            ps[rg * 8 + r][lane] = p;
            if (lane == 0) wsc[rg * 8 + r] = sc;
        }
        // ---- PV: acc[f] = acc[f]*sc + sum_jj p[jj]*h[jj][f] ----
        float sc = wsc[r_pv];
#pragma unroll
        for (int q = 0; q < 8; q++) {
            acc[q].x *= sc; acc[q].y *= sc; acc[q].z *= sc; acc[q].w *= sc;
        }
        for (int jj = 0; jj < 64; jj++) {
            float p = ps[r_pv][jj];
#pragma unroll
            for (int q = 0; q < 8; q++) {
                float4 hv = hs4[jj][fg * 8 + ((q + fg) & 7)];
                acc[q].x += p * hv.x;
                acc[q].y += p * hv.y;
                acc[q].z += p * hv.z;
                acc[q].w += p * hv.w;
            }
        }
    }

    // ---- finalize: denominator reduce + write ----
#pragma unroll
    for (int r = 0; r < 8; r++) {
        float ls = l[r];
#pragma unroll
        for (int d = 32; d; d >>= 1) ls += __shfl_xor(ls, d);
        if (lane == 0) winv[rg * 8 + r] = 1.0f / ls;
    }
    float inv = winv[r_pv];
#pragma unroll
    for (int q = 0; q < 8; q++) {
        float4 v = acc[q];
        v.x *= inv; v.y *= inv; v.z *= inv; v.w *= inv;
        *(float4*)&out[((size_t)(b * Nn + i0 + r_pv)) * Ff + fg * 32 + q * 4] = v;
    }
}

extern "C" void kernel_launch(void* const* d_in, const int* in_sizes, int n_in,
                              void* d_out, int out_size, void* d_ws, size_t ws_size,
                              hipStream_t stream) {
    const float* X    = (const float*)d_in[0];   // (B,N,F)
    const float* Ageo = (const float*)d_in[1];   // (N,N)
    const float* Dm   = (const float*)d_in[2];   // (N,N)
    const float* Ww   = (const float*)d_in[3];   // (F,F)
    const float* Wb   = (const float*)d_in[4];   // (F,)
    const float* a1   = (const float*)d_in[5];   // (F,)
    const float* a2   = (const float*)d_in[6];   // (F,)
    const float* ab   = (const float*)d_in[7];   // (1,)
    const float* thr  = (const float*)d_in[8];   // (1,)
    float* out = (float*)d_out;

    float* ws   = (float*)d_ws;
    float* h    = ws;                                  // B*N*F   = 4,194,304
    float* mask = h    + (size_t)Bsz * Nn * Ff;        // N*N     = 4,194,304
    float* g    = mask + (size_t)Nn * Nn;              // N*N
    float* s1   = g    + (size_t)Nn * Nn;              // B*N = 16384
    float* s2   = s1   + (size_t)Bsz * Nn;
    float* Wt   = s2   + (size_t)Bsz * Nn;             // F*F = 65536

    k_pre<<<(Nn * Nn / 4) / 256, 256, 0, stream>>>(Ageo, Dm, thr, mask, g);
    k_wt<<<Ff, Ff, 0, stream>>>(Ww, Wt);
    k_h<<<(Bsz * Nn) / 32, 256, 0, stream>>>(X, Wt, Wb, a1, a2, h, s1, s2);
    k_attn<<<dim3(Nn / 32, Bsz), 256, 0, stream>>>(h, s1, s2, mask, g, ab, out);
}

// Round 2
// 132.320 us; speedup vs baseline: 3.4176x; 3.4176x over previous
//
#include <hip/hip_runtime.h>
#include <hip/hip_bf16.h>
#include <math.h>

#define Bsz 8
#define Nn  2048
#define Ff  256

typedef short short8 __attribute__((ext_vector_type(8)));
typedef float f32x4  __attribute__((ext_vector_type(4)));
typedef unsigned short u16x8 __attribute__((ext_vector_type(8)));

static __device__ __forceinline__ unsigned short f2bf(float v) {
    __hip_bfloat16 b = __float2bfloat16(v);
    return *reinterpret_cast<unsigned short*>(&b);
}

// ---------------- k_pre: mask = sigmoid(10*(A-thr)); g = mask / (D+1e-5), diag(D)=1 ----------
__global__ __launch_bounds__(256) void k_pre(const float* __restrict__ Ageo,
                                             const float* __restrict__ Dm,
                                             const float* __restrict__ thr_p,
                                             float* __restrict__ mask,
                                             float* __restrict__ g) {
    int idx4 = blockIdx.x * 256 + threadIdx.x;
    float thr = thr_p[0];
    float4 a = ((const float4*)Ageo)[idx4];
    float4 d = ((const float4*)Dm)[idx4];
    int i  = idx4 >> 9;
    int j0 = (idx4 & 511) << 2;
    float av[4] = {a.x, a.y, a.z, a.w};
    float dv[4] = {d.x, d.y, d.z, d.w};
    float mo[4], go[4];
#pragma unroll
    for (int k = 0; k < 4; k++) {
        float dd  = (j0 + k == i) ? 1.0f : dv[k];
        float inv = 1.0f / (dd + 1e-5f);
        float mk  = 1.0f / (1.0f + __expf(-10.0f * (av[k] - thr)));
        mo[k] = mk;
        go[k] = mk * inv;
    }
    ((float4*)mask)[idx4] = make_float4(mo[0], mo[1], mo[2], mo[3]);
    ((float4*)g)[idx4]    = make_float4(go[0], go[1], go[2], go[3]);
}

// ---------------- k_wt: Wt[f][o] = W[o][f] ----------------
__global__ __launch_bounds__(256) void k_wt(const float* __restrict__ W,
                                            float* __restrict__ Wt) {
    int o = blockIdx.x;
    int f = threadIdx.x;
    Wt[f * Ff + o] = W[o * Ff + f];
}

// ---------------- k_h: h = X @ W^T + b ; writes hT (B,F,N) bf16 ; s1 ; s2 ----
__global__ __launch_bounds__(256) void k_h(const float* __restrict__ X,
                                           const float* __restrict__ Wt,
                                           const float* __restrict__ Wb,
                                           const float* __restrict__ a1,
                                           const float* __restrict__ a2,
                                           unsigned short* __restrict__ hT,
                                           float* __restrict__ s1,
                                           float* __restrict__ s2) {
    int wid  = blockIdx.x * 4 + (threadIdx.x >> 6);
    int lane = threadIdx.x & 63;
    int r0   = wid * 8;
    int o0   = lane * 4;

    float4 acc[8];
#pragma unroll
    for (int r = 0; r < 8; r++) acc[r] = make_float4(0.f, 0.f, 0.f, 0.f);

    for (int f0 = 0; f0 < Ff; f0 += 4) {
        float4 wv0 = *(const float4*)&Wt[(f0 + 0) * Ff + o0];
        float4 wv1 = *(const float4*)&Wt[(f0 + 1) * Ff + o0];
        float4 wv2 = *(const float4*)&Wt[(f0 + 2) * Ff + o0];
        float4 wv3 = *(const float4*)&Wt[(f0 + 3) * Ff + o0];
#pragma unroll
        for (int r = 0; r < 8; r++) {
            float4 xv = *(const float4*)&X[(size_t)(r0 + r) * Ff + f0];
            acc[r].x += xv.x * wv0.x + xv.y * wv1.x + xv.z * wv2.x + xv.w * wv3.x;
            acc[r].y += xv.x * wv0.y + xv.y * wv1.y + xv.z * wv2.y + xv.w * wv3.y;
            acc[r].z += xv.x * wv0.z + xv.y * wv1.z + xv.z * wv2.z + xv.w * wv3.z;
            acc[r].w += xv.x * wv0.w + xv.y * wv1.w + xv.z * wv2.w + xv.w * wv3.w;
        }
    }

    float4 wb  = *(const float4*)&Wb[o0];
    float4 a1v = *(const float4*)&a1[o0];
    float4 a2v = *(const float4*)&a2[o0];

    float4 hv[8];
#pragma unroll
    for (int r = 0; r < 8; r++) {
        hv[r] = make_float4(acc[r].x + wb.x, acc[r].y + wb.y,
                            acc[r].z + wb.z, acc[r].w + wb.w);
        float d1 = hv[r].x * a1v.x + hv[r].y * a1v.y + hv[r].z * a1v.z + hv[r].w * a1v.w;
        float d2 = hv[r].x * a2v.x + hv[r].y * a2v.y + hv[r].z * a2v.z + hv[r].w * a2v.w;
#pragma unroll
        for (int d = 32; d; d >>= 1) {
            d1 += __shfl_xor(d1, d);
            d2 += __shfl_xor(d2, d);
        }
        if (lane == 0) {
            s1[r0 + r] = d1;
            s2[r0 + r] = d2;
        }
    }

    int b  = r0 >> 11;
    int n0 = r0 & 2047;
#pragma unroll
    for (int c = 0; c < 4; c++) {
        u16x8 pk;
#pragma unroll
        for (int r = 0; r < 8; r++) pk[r] = f2bf((&hv[r].x)[c]);
        *(u16x8*)&hT[((size_t)(b * Ff + o0 + c)) * Nn + n0] = pk;
    }
}

// ---------------- k_rmax: gmax[i] = max_j g[i][j];  s2max[b] = max_n s2[b][n] ----
__global__ __launch_bounds__(256) void k_rmax(const float* __restrict__ g,
                                              const float* __restrict__ s2,
                                              float* __restrict__ gmax,
                                              float* __restrict__ s2max) {
    int bid = blockIdx.x;
    const float* src;
    float* dst;
    if (bid < Nn) { src = g + (size_t)bid * Nn;          dst = gmax + bid; }
    else          { src = s2 + (size_t)(bid - Nn) * Nn;  dst = s2max + (bid - Nn); }
    int tid = threadIdx.x;
    float m = -1e30f;
    for (int i = tid; i < Nn; i += 256) m = fmaxf(m, src[i]);
#pragma unroll
    for (int d = 32; d; d >>= 1) m = fmaxf(m, __shfl_xor(m, d));
    __shared__ float red[4];
    if ((tid & 63) == 0) red[tid >> 6] = m;
    __syncthreads();
    if (tid == 0) *dst = fmaxf(fmaxf(red[0], red[1]), fmaxf(red[2], red[3]));
}

// ---------------- k_attn: scores (bounded softmax) + MFMA PV --------------------
// block: 256 thr / 4 waves; 32 query rows; chunk 64 keys; wave w owns f [w*64, w*64+64)
__global__ __launch_bounds__(256) void k_attn(const unsigned short* __restrict__ hT,
                                              const float* __restrict__ s1,
                                              const float* __restrict__ s2,
                                              const float* __restrict__ mask,
                                              const float* __restrict__ g,
                                              const float* __restrict__ gmax,
                                              const float* __restrict__ s2max,
                                              const float* __restrict__ ab_p,
                                              float* __restrict__ out) {
    __shared__ char ht_lds[32768];   // [256 f][64 k] bf16, XOR-swizzled (byte ^= (f&7)<<4)
    __shared__ char p_lds[4096];     // [32 q][64 k] bf16, XOR-swizzled (byte ^= (q&7)<<4)
    __shared__ float linv[32];

    const int b    = blockIdx.y;
    const int i0   = blockIdx.x * 32;
    const int tid  = threadIdx.x;
    const int lane = tid & 63;
    const int w    = tid >> 6;
    const float ab  = ab_p[0];
    const float s2m = s2max[b];

    float s1v[8], M[8], lsum[8];
#pragma unroll
    for (int r = 0; r < 8; r++) {
        int q = w * 8 + r;
        float sv = s1[b * Nn + i0 + q];
        s1v[r] = sv;
        float sb = sv + s2m + ab;
        M[r] = (sb > 0.f ? sb : 0.f) + gmax[i0 + q];
        lsum[r] = 0.f;
    }

    f32x4 acc[2][4];
#pragma unroll
    for (int mt = 0; mt < 2; mt++)
#pragma unroll
        for (int nt = 0; nt < 4; nt++) acc[mt][nt] = (f32x4)0.f;

    for (int j0 = 0; j0 < Nn; j0 += 64) {
        // ---- stage hT chunk -> LDS (linear dest, inverse-swizzled source) ----
#pragma unroll
        for (int it = 0; it < 8; it++) {
            int s  = (w + 4 * it) * 64 + lane;   // 16B slot index
            int f  = s >> 3;
            int kb = s & 7;
            const unsigned short* src = hT + ((size_t)(b * Ff + f)) * Nn + j0 + ((kb ^ (f & 7)) << 3);
            __builtin_amdgcn_global_load_lds((const __attribute__((address_space(1))) void*)src,
                                             (__attribute__((address_space(3))) void*)(ht_lds + (w + 4 * it) * 1024),
                                             16, 0, 0);
        }

        // ---- scores: p = exp(e - M), write bf16 to p_lds (overlaps staging latency) ----
        float s2j = s2[b * Nn + j0 + lane];
#pragma unroll
        for (int r = 0; r < 8; r++) {
            int q = w * 8 + r;
            size_t off = (size_t)(i0 + q) * Nn + j0 + lane;
            float mk = mask[off];
            float gg = g[off];
            float sv = s1v[r] + s2j + ab;
            sv = sv > 0.f ? sv : 0.1f * sv;
            float p = __expf(sv * mk + gg - M[r]);
            lsum[r] += p;
            int byte = (q * 128 + lane * 2) ^ ((q & 7) << 4);
            *(unsigned short*)(p_lds + byte) = f2bf(p);
        }
        __syncthreads();   // stage complete (vmcnt drain) + p visible

        // ---- PV: 16 MFMA per wave ----
        short8 afr[2][2];
#pragma unroll
        for (int mt = 0; mt < 2; mt++)
#pragma unroll
            for (int kt = 0; kt < 2; kt++) {
                int q = mt * 16 + (lane & 15);
                int byte = (q * 128 + kt * 64 + (lane >> 4) * 16) ^ ((q & 7) << 4);
                afr[mt][kt] = *(const short8*)(p_lds + byte);
            }
#pragma unroll
        for (int nt = 0; nt < 4; nt++) {
            int f = w * 64 + nt * 16 + (lane & 15);
#pragma unroll
            for (int kt = 0; kt < 2; kt++) {
                int byte = (f * 128 + kt * 64 + (lane >> 4) * 16) ^ ((f & 7) << 4);
                short8 bfr = *(const short8*)(ht_lds + byte);
                acc[0][nt] = __builtin_amdgcn_mfma_f32_16x16x32_bf16(afr[0][kt], bfr, acc[0][nt], 0, 0, 0);
                acc[1][nt] = __builtin_amdgcn_mfma_f32_16x16x32_bf16(afr[1][kt], bfr, acc[1][nt], 0, 0, 0);
            }
        }
        __syncthreads();   // ht_lds / p_lds safe to overwrite
    }

    // ---- denominators ----
#pragma unroll
    for (int r = 0; r < 8; r++) {
        float ls = lsum[r];
#pragma unroll
        for (int d = 32; d; d >>= 1) ls += __shfl_xor(ls, d);
        if (lane == 0) linv[w * 8 + r] = 1.0f / ls;
    }
    __syncthreads();

    // ---- write out: lane holds D[q=(l>>4)*4+reg][f=l&15] per (mt,nt) tile ----
#pragma unroll
    for (int mt = 0; mt < 2; mt++) {
#pragma unroll
        for (int reg = 0; reg < 4; reg++) {
            int q = mt * 16 + (lane >> 4) * 4 + reg;
            float inv = linv[q];
            size_t base = ((size_t)(b * Nn + i0 + q)) * Ff + w * 64 + (lane & 15);
#pragma unroll
            for (int nt = 0; nt < 4; nt++) {
                out[base + nt * 16] = acc[mt][nt][reg] * inv;
            }
        }
    }
}

extern "C" void kernel_launch(void* const* d_in, const int* in_sizes, int n_in,
                              void* d_out, int out_size, void* d_ws, size_t ws_size,
                              hipStream_t stream) {
    const float* X    = (const float*)d_in[0];
    const float* Ageo = (const float*)d_in[1];
    const float* Dm   = (const float*)d_in[2];
    const float* Ww   = (const float*)d_in[3];
    const float* Wb   = (const float*)d_in[4];
    const float* a1   = (const float*)d_in[5];
    const float* a2   = (const float*)d_in[6];
    const float* ab   = (const float*)d_in[7];
    const float* thr  = (const float*)d_in[8];
    float* out = (float*)d_out;

    float* ws    = (float*)d_ws;
    float* mask  = ws;                                   // N*N
    float* g     = mask  + (size_t)Nn * Nn;              // N*N
    float* s1    = g     + (size_t)Nn * Nn;              // B*N
    float* s2    = s1    + (size_t)Bsz * Nn;             // B*N
    float* Wt    = s2    + (size_t)Bsz * Nn;             // F*F
    float* gmax  = Wt    + (size_t)Ff * Ff;              // N
    float* s2max = gmax  + Nn;                           // B
    unsigned short* hT = (unsigned short*)(s2max + Bsz); // B*F*N bf16 (16B-aligned)

    k_pre<<<(Nn * Nn / 4) / 256, 256, 0, stream>>>(Ageo, Dm, thr, mask, g);
    k_wt<<<Ff, Ff, 0, stream>>>(Ww, Wt);
    k_h<<<(Bsz * Nn) / 32, 256, 0, stream>>>(X, Wt, Wb, a1, a2, hT, s1, s2);
    k_rmax<<<Nn + Bsz, 256, 0, stream>>>(g, s2, gmax, s2max);
    k_attn<<<dim3(Nn / 32, Bsz), 256, 0, stream>>>(hT, s1, s2, mask, g, gmax, s2max, ab, out);
}

// Round 3
// 98.116 us; speedup vs baseline: 4.6090x; 1.3486x over previous
//
#include <hip/hip_runtime.h>
#include <hip/hip_bf16.h>
#include <math.h>

#define Bsz 8
#define Nn  2048
#define Ff  256

typedef short short8 __attribute__((ext_vector_type(8)));
typedef float f32x4  __attribute__((ext_vector_type(4)));
typedef unsigned short u16x4 __attribute__((ext_vector_type(4)));

static __device__ __forceinline__ unsigned short f2bf(float v) {
    __hip_bfloat16 b = __float2bfloat16(v);
    return *reinterpret_cast<unsigned short*>(&b);
}
static __device__ __forceinline__ float fast_rcp(float x) {
    return __builtin_amdgcn_rcpf(x);
}

// ---------------- k_gmax: gmax[i] = max_j sigmoid(10(A-thr)) / (D+1e-5), diag(D)=1 ----------
__global__ __launch_bounds__(256) void k_gmax(const float* __restrict__ Ageo,
                                              const float* __restrict__ Dm,
                                              const float* __restrict__ thr_p,
                                              float* __restrict__ gmax) {
    const int i   = blockIdx.x;
    const int tid = threadIdx.x;
    const float c10 = 10.0f * thr_p[0];
    float m = 0.0f;
#pragma unroll
    for (int p = 0; p < 2; p++) {
        int j = tid * 4 + p * 1024;
        float4 a = *(const float4*)&Ageo[(size_t)i * Nn + j];
        float4 d = *(const float4*)&Dm[(size_t)i * Nn + j];
        float av[4] = {a.x, a.y, a.z, a.w};
        float dv[4] = {d.x, d.y, d.z, d.w};
#pragma unroll
        for (int c = 0; c < 4; c++) {
            float dd = (j + c == i) ? 1.0f : dv[c];
            float mk = fast_rcp(1.0f + __expf(c10 - 10.0f * av[c]));
            float g  = mk * fast_rcp(dd + 1e-5f);
            m = fmaxf(m, g);
        }
    }
#pragma unroll
    for (int d = 32; d; d >>= 1) m = fmaxf(m, __shfl_xor(m, d));
    __shared__ float red[4];
    if ((tid & 63) == 0) red[tid >> 6] = m;
    __syncthreads();
    if (tid == 0) gmax[i] = fmaxf(fmaxf(red[0], red[1]), fmaxf(red[2], red[3]));
}

// ---------------- k_h: MFMA bf16  h = X@W^T + b -> hT (B,F,N) bf16 ; s1 ; s2 -----------
// block: 256 thr / 4 waves; 64 rows (n); all 256 cols (o); wave w owns o in [w*64, w*64+64)
__global__ __launch_bounds__(256) void k_h(const float* __restrict__ X,
                                           const float* __restrict__ W,
                                           const float* __restrict__ Wb,
                                           const float* __restrict__ a1,
                                           const float* __restrict__ a2,
                                           unsigned short* __restrict__ hT,
                                           float* __restrict__ s1,
                                           float* __restrict__ s2) {
    __shared__ char  w_lds[32768];            // [256 o][64 f] bf16, byte ^= (o&7)<<4
    __shared__ char  x_lds[8192];             // [64 n][64 f] bf16, byte ^= (n&7)<<4
    __shared__ float sred1[4][4][16];
    __shared__ float sred2[4][4][16];

    const int tid  = threadIdx.x;
    const int lane = tid & 63;
    const int w    = tid >> 6;
    const int r0   = blockIdx.x * 64;
    const int b    = r0 >> 11;
    const int n0   = r0 & 2047;

    f32x4 acc[4][4];
#pragma unroll
    for (int mt = 0; mt < 4; mt++)
#pragma unroll
        for (int nt = 0; nt < 4; nt++) acc[mt][nt] = (f32x4)0.f;

    for (int kc = 0; kc < 4; kc++) {
        const int f0 = kc * 64;
        __syncthreads();
        // stage W chunk [256 o][64 f]
#pragma unroll
        for (int p = 0; p < 16; p++) {
            int idx = tid + p * 256;
            int o = idx >> 4, fi = idx & 15;
            float4 v = *(const float4*)&W[(size_t)o * Ff + f0 + fi * 4];
            u16x4 pk = {f2bf(v.x), f2bf(v.y), f2bf(v.z), f2bf(v.w)};
            *(u16x4*)(w_lds + ((o * 128 + fi * 8) ^ ((o & 7) << 4))) = pk;
        }
        // stage X chunk [64 n][64 f]
#pragma unroll
        for (int p = 0; p < 4; p++) {
            int idx = tid + p * 256;
            int n = idx >> 4, fi = idx & 15;
            float4 v = *(const float4*)&X[(size_t)(r0 + n) * Ff + f0 + fi * 4];
            u16x4 pk = {f2bf(v.x), f2bf(v.y), f2bf(v.z), f2bf(v.w)};
            *(u16x4*)(x_lds + ((n * 128 + fi * 8) ^ ((n & 7) << 4))) = pk;
        }
        __syncthreads();
#pragma unroll
        for (int kt = 0; kt < 2; kt++) {
            short8 bfr[4];
#pragma unroll
            for (int nt = 0; nt < 4; nt++) {
                int n = nt * 16 + (lane & 15);
                bfr[nt] = *(const short8*)(x_lds + ((n * 128 + kt * 64 + (lane >> 4) * 16) ^ ((n & 7) << 4)));
            }
#pragma unroll
            for (int mt = 0; mt < 4; mt++) {
                int o = w * 64 + mt * 16 + (lane & 15);
                short8 afr = *(const short8*)(w_lds + ((o * 128 + kt * 64 + (lane >> 4) * 16) ^ ((o & 7) << 4)));
#pragma unroll
                for (int nt = 0; nt < 4; nt++)
                    acc[mt][nt] = __builtin_amdgcn_mfma_f32_16x16x32_bf16(afr, bfr[nt], acc[mt][nt], 0, 0, 0);
            }
        }
    }

    // epilogue: bias, hT write, s1/s2 partials
    float s1p[4] = {0.f, 0.f, 0.f, 0.f};
    float s2p[4] = {0.f, 0.f, 0.f, 0.f};
#pragma unroll
    for (int mt = 0; mt < 4; mt++) {
#pragma unroll
        for (int reg = 0; reg < 4; reg++) {
            int o = w * 64 + mt * 16 + (lane >> 4) * 4 + reg;
            float wb = Wb[o], a1v = a1[o], a2v = a2[o];
#pragma unroll
            for (int nt = 0; nt < 4; nt++) {
                float hv = acc[mt][nt][reg] + wb;
                int n = n0 + nt * 16 + (lane & 15);
                hT[((size_t)(b * Ff + o)) * Nn + n] = f2bf(hv);
                s1p[nt] += hv * a1v;
                s2p[nt] += hv * a2v;
            }
        }
    }
#pragma unroll
    for (int nt = 0; nt < 4; nt++) {
        s1p[nt] += __shfl_xor(s1p[nt], 16); s1p[nt] += __shfl_xor(s1p[nt], 32);
        s2p[nt] += __shfl_xor(s2p[nt], 16); s2p[nt] += __shfl_xor(s2p[nt], 32);
    }
    if (lane < 16) {
#pragma unroll
        for (int nt = 0; nt < 4; nt++) { sred1[w][nt][lane] = s1p[nt]; sred2[w][nt][lane] = s2p[nt]; }
    }
    __syncthreads();
    if (tid < 64) {
        int nt = tid >> 4, col = tid & 15;
        s1[b * Nn + n0 + nt * 16 + col] = sred1[0][nt][col] + sred1[1][nt][col] + sred1[2][nt][col] + sred1[3][nt][col];
    } else if (tid < 128) {
        int t2 = tid - 64;
        int nt = t2 >> 4, col = t2 & 15;
        s2[b * Nn + n0 + nt * 16 + col] = sred2[0][nt][col] + sred2[1][nt][col] + sred2[2][nt][col] + sred2[3][nt][col];
    }
}

// ---------------- k_s2max ----------------
__global__ __launch_bounds__(256) void k_s2max(const float* __restrict__ s2,
                                               float* __restrict__ s2max) {
    int b = blockIdx.x, tid = threadIdx.x;
    float m = -1e30f;
    for (int k = tid; k < Nn; k += 256) m = fmaxf(m, s2[b * Nn + k]);
#pragma unroll
    for (int d = 32; d; d >>= 1) m = fmaxf(m, __shfl_xor(m, d));
    __shared__ float red[4];
    if ((tid & 63) == 0) red[tid >> 6] = m;
    __syncthreads();
    if (tid == 0) s2max[b] = fmaxf(fmaxf(red[0], red[1]), fmaxf(red[2], red[3]));
}

// ---------------- k_attn: inline scores + bounded softmax + MFMA PV, pipelined --------
__global__ __launch_bounds__(256) void k_attn(const unsigned short* __restrict__ hT,
                                              const float* __restrict__ s1,
                                              const float* __restrict__ s2,
                                              const float* __restrict__ Ageo,
                                              const float* __restrict__ Dm,
                                              const float* __restrict__ gmax,
                                              const float* __restrict__ s2max,
                                              const float* __restrict__ ab_p,
                                              const float* __restrict__ thr_p,
                                              float* __restrict__ out) {
    __shared__ char ht_lds[2][32768];   // [256 f][64 k] bf16, byte ^= (f&7)<<4
    __shared__ char p_lds[2][4096];     // [32 q][64 k] bf16, byte ^= (q&7)<<4
    __shared__ float linv[32];

    const int bid  = blockIdx.x;
    const int b    = bid & 7;            // XCD-slot: all blocks of b land on one XCD's L2
    const int i0   = (bid >> 3) * 32;
    const int tid  = threadIdx.x;
    const int lane = tid & 63;
    const int w    = tid >> 6;
    const float ab  = ab_p[0];
    const float c10 = 10.0f * thr_p[0];
    const float s2m = s2max[b];

    float s1ab[8], M[8], lsum[8];
#pragma unroll
    for (int r = 0; r < 8; r++) {
        int q = w * 8 + r;
        float sv = s1[b * Nn + i0 + q];
        s1ab[r] = sv + ab;
        float sb = sv + s2m + ab;
        M[r] = (sb > 0.f ? sb : 0.f) + gmax[i0 + q];
        lsum[r] = 0.f;
    }

    f32x4 acc[2][4];
#pragma unroll
    for (int mt = 0; mt < 2; mt++)
#pragma unroll
        for (int nt = 0; nt < 4; nt++) acc[mt][nt] = (f32x4)0.f;

    auto stage = [&](int t, char* buf) {
        int j0 = t * 64;
#pragma unroll
        for (int it = 0; it < 8; it++) {
            int s  = (w + 4 * it) * 64 + lane;
            int f  = s >> 3;
            int kb = s & 7;
            const unsigned short* src = hT + ((size_t)(b * Ff + f)) * Nn + j0 + ((kb ^ (f & 7)) << 3);
            __builtin_amdgcn_global_load_lds((const __attribute__((address_space(1))) void*)src,
                                             (__attribute__((address_space(3))) void*)(buf + (w + 4 * it) * 1024),
                                             16, 0, 0);
        }
    };
    auto prefetch = [&](int t, float (&Av)[8], float (&Dv)[8], float& s2j) {
        int j = t * 64 + lane;
        s2j = s2[b * Nn + j];
#pragma unroll
        for (int r = 0; r < 8; r++) {
            size_t off = (size_t)(i0 + w * 8 + r) * Nn + j;
            Av[r] = Ageo[off];
            Dv[r] = Dm[off];
        }
    };
    auto scores = [&](int t, float (&Av)[8], float (&Dv)[8], float s2j, char* pb) {
        int j = t * 64 + lane;
#pragma unroll
        for (int r = 0; r < 8; r++) {
            int q = w * 8 + r;
            float s = s1ab[r] + s2j;
            s = s > 0.f ? s : 0.1f * s;
            float mk = fast_rcp(1.0f + __expf(c10 - 10.0f * Av[r]));
            float dd = (i0 + q == j) ? 1.0f : Dv[r];
            float gg = mk * fast_rcp(dd + 1e-5f);
            float p = __expf(s * mk + gg - M[r]);
            lsum[r] += p;
            int byte = (q * 128 + lane * 2) ^ ((q & 7) << 4);
            *(unsigned short*)(pb + byte) = f2bf(p);
        }
    };
    auto domfma = [&](char* pb, char* htb) {
        short8 afr[2][2];
#pragma unroll
        for (int mt = 0; mt < 2; mt++)
#pragma unroll
            for (int kt = 0; kt < 2; kt++) {
                int q = mt * 16 + (lane & 15);
                int byte = (q * 128 + kt * 64 + (lane >> 4) * 16) ^ ((q & 7) << 4);
                afr[mt][kt] = *(const short8*)(pb + byte);
            }
#pragma unroll
        for (int nt = 0; nt < 4; nt++) {
            int f = w * 64 + nt * 16 + (lane & 15);
#pragma unroll
            for (int kt = 0; kt < 2; kt++) {
                int byte = (f * 128 + kt * 64 + (lane >> 4) * 16) ^ ((f & 7) << 4);
                short8 bfr = *(const short8*)(htb + byte);
                acc[0][nt] = __builtin_amdgcn_mfma_f32_16x16x32_bf16(afr[0][kt], bfr, acc[0][nt], 0, 0, 0);
                acc[1][nt] = __builtin_amdgcn_mfma_f32_16x16x32_bf16(afr[1][kt], bfr, acc[1][nt], 0, 0, 0);
            }
        }
    };

    float Av0[8], Dv0[8], Av1[8], Dv1[8];
    float s2j0, s2j1;

    // prologue
    stage(0, ht_lds[0]);
    prefetch(0, Av0, Dv0, s2j0);

    for (int tt = 0; tt < 16; tt++) {
        const int t0 = tt * 2;
        // phase A: t = t0 (buf 0, regs set0 -> set1)
        prefetch(t0 + 1, Av1, Dv1, s2j1);
        scores(t0, Av0, Dv0, s2j0, p_lds[0]);
        __syncthreads();                        // drains stage(t0) + p visible
        domfma(p_lds[0], ht_lds[0]);
        stage(t0 + 1, ht_lds[1]);
        // phase B: t = t0+1 (buf 1, regs set1 -> set0)
        {
            int tn = (t0 + 2 < 32) ? t0 + 2 : 31;
            prefetch(tn, Av0, Dv0, s2j0);
            scores(t0 + 1, Av1, Dv1, s2j1, p_lds[1]);
            __syncthreads();
            domfma(p_lds[1], ht_lds[1]);
            stage(tn, ht_lds[0]);
        }
    }

    // denominators
#pragma unroll
    for (int r = 0; r < 8; r++) {
        float ls = lsum[r];
#pragma unroll
        for (int d = 32; d; d >>= 1) ls += __shfl_xor(ls, d);
        if (lane == 0) linv[w * 8 + r] = 1.0f / ls;
    }
    __syncthreads();

#pragma unroll
    for (int mt = 0; mt < 2; mt++) {
#pragma unroll
        for (int reg = 0; reg < 4; reg++) {
            int q = mt * 16 + (lane >> 4) * 4 + reg;
            float inv = linv[q];
            size_t base = ((size_t)(b * Nn + i0 + q)) * Ff + w * 64 + (lane & 15);
#pragma unroll
            for (int nt = 0; nt < 4; nt++) {
                out[base + nt * 16] = acc[mt][nt][reg] * inv;
            }
        }
    }
}

extern "C" void kernel_launch(void* const* d_in, const int* in_sizes, int n_in,
                              void* d_out, int out_size, void* d_ws, size_t ws_size,
                              hipStream_t stream) {
    const float* X    = (const float*)d_in[0];
    const float* Ageo = (const float*)d_in[1];
    const float* Dm   = (const float*)d_in[2];
    const float* Ww   = (const float*)d_in[3];
    const float* Wb   = (const float*)d_in[4];
    const float* a1   = (const float*)d_in[5];
    const float* a2   = (const float*)d_in[6];
    const float* ab   = (const float*)d_in[7];
    const float* thr  = (const float*)d_in[8];
    float* out = (float*)d_out;

    float* ws    = (float*)d_ws;
    float* gmax  = ws;                                   // N
    float* s2max = gmax  + Nn;                           // B
    float* s1    = s2max + Bsz;                          // B*N
    float* s2    = s1    + (size_t)Bsz * Nn;             // B*N
    unsigned short* hT = (unsigned short*)(s2 + (size_t)Bsz * Nn);  // B*F*N bf16

    k_gmax<<<Nn, 256, 0, stream>>>(Ageo, Dm, thr, gmax);
    k_h<<<(Bsz * Nn) / 64, 256, 0, stream>>>(X, Ww, Wb, a1, a2, hT, s1, s2);
    k_s2max<<<Bsz, 256, 0, stream>>>(s2, s2max);
    k_attn<<<Nn / 32 * Bsz, 256, 0, stream>>>(hT, s1, s2, Ageo, Dm, gmax, s2max, ab, thr, out);
}